// Round 4
// baseline (671.244 us; speedup 1.0000x reference)
//
#include <hip/hip_runtime.h>
#include <math.h>

// TopK router: logits = x @ W^T (fp32), top-2 per token + softmax over the 2.
// x: [nTok, D] fp32, W: [E=64, D] fp32.
// out: [probs (nTok*2 f32)] ++ [idx (nTok*2, written as f32 values)]
//
// Structure: block = 8 waves (512 thr) over 16 tokens; K split 8-ways across
// waves. Lane = (t = lane>>2 token, s = lane&3 k-subslice). Main loop has NO
// LDS and NO barriers: x streamed nontemporal (each 64B line used exactly
// once), W vector-loaded (L1/L2-hot, 1 line per expert per iter), acc[64]
// statically indexed. Epilogue: shfl butterfly over s, LDS cross-wave sum,
// 16-thread strict-'>' top-2 (lowest index on ties = jax.lax.top_k) + softmax.

typedef float f32x4 __attribute__((ext_vector_type(4)));

#define TOKB 16
#define NW 8
#define THREADS (NW * 64)
#define NE 64
#define LDE 68   // padded: stride 68 -> bank 4t, 2-way (free); 16B-aligned

__global__ __launch_bounds__(THREADS, 4)
void router_main(const float* __restrict__ x, const float* __restrict__ W,
                 float* __restrict__ out_probs, float* __restrict__ out_idx,
                 int D) {
  __shared__ float red[NW][TOKB][LDE];   // 8*16*68*4 = 34.8 KB
  __shared__ float logit[TOKB][LDE];     // 4.3 KB

  const int tid  = threadIdx.x;
  const int w    = tid >> 6;
  const int lane = tid & 63;
  const int t    = lane >> 2;     // token within block
  const int s    = lane & 3;      // k sub-slice within wave's K range
  const int m0   = blockIdx.x * TOKB;

  const int Ks  = D / NW;         // 512 k per wave
  const int kb  = w * Ks + s * 4; // lane's first k
  const int NIT = Ks / 16;        // 32 iters, 16 k per wave-iter

  const float* xp = x + (size_t)(m0 + t) * D + kb;
  const float* wp = W + kb;

  float acc[NE];
#pragma unroll
  for (int e = 0; e < NE; ++e) acc[e] = 0.f;

  f32x4 xv = __builtin_nontemporal_load(reinterpret_cast<const f32x4*>(xp));

#pragma unroll 1
  for (int it = 0; it < NIT - 1; ++it) {
    const f32x4 xn = __builtin_nontemporal_load(
        reinterpret_cast<const f32x4*>(xp + 16));
    xp += 16;
    const float* wr = wp;
#pragma unroll
    for (int e = 0; e < NE; ++e) {
      const f32x4 wv = *reinterpret_cast<const f32x4*>(wr + (size_t)e * D);
      acc[e] = fmaf(xv.x, wv.x, acc[e]);
      acc[e] = fmaf(xv.y, wv.y, acc[e]);
      acc[e] = fmaf(xv.z, wv.z, acc[e]);
      acc[e] = fmaf(xv.w, wv.w, acc[e]);
    }
    wp += 16;
    xv = xn;
  }
  {
    const float* wr = wp;
#pragma unroll
    for (int e = 0; e < NE; ++e) {
      const f32x4 wv = *reinterpret_cast<const f32x4*>(wr + (size_t)e * D);
      acc[e] = fmaf(xv.x, wv.x, acc[e]);
      acc[e] = fmaf(xv.y, wv.y, acc[e]);
      acc[e] = fmaf(xv.z, wv.z, acc[e]);
      acc[e] = fmaf(xv.w, wv.w, acc[e]);
    }
  }

  // ---- reduce over the 4 k-subslices (lanes t*4+0..3) via butterfly ----
#pragma unroll
  for (int e = 0; e < NE; ++e) {
    acc[e] += __shfl_xor(acc[e], 1, 64);
    acc[e] += __shfl_xor(acc[e], 2, 64);
  }

  // ---- write per-wave partials: lane with s==g owns expert group g ----
  // (predicated stores keep acc[] statically indexed; 16 active lanes each,
  //  stride LDE=68 floats -> banks 4t: 2-way aliasing = free)
#pragma unroll
  for (int j4 = 0; j4 < NE; j4 += 4) {
    if (s == (j4 >> 4)) {
      *reinterpret_cast<float4*>(&red[w][t][j4]) =
          make_float4(acc[j4], acc[j4 + 1], acc[j4 + 2], acc[j4 + 3]);
    }
  }
  __syncthreads();

  // ---- cross-wave sum: 1024 (t,e) pairs over 512 threads ----
#pragma unroll
  for (int rep = 0; rep < 2; ++rep) {
    const int j  = tid + rep * THREADS;
    const int tt = j >> 6;
    const int e  = j & 63;
    float v = 0.f;
#pragma unroll
    for (int ww = 0; ww < NW; ++ww) v += red[ww][tt][e];
    logit[tt][e] = v;
  }
  __syncthreads();

  // ---- top-2 + softmax: one thread per token ----
  if (tid < TOKB) {
    float b0 = -INFINITY, b1 = -INFINITY;
    int i0 = 0, i1 = 0;
    const float* row = &logit[tid][0];
#pragma unroll
    for (int e4 = 0; e4 < NE / 4; ++e4) {
      const float4 v = *reinterpret_cast<const float4*>(row + e4 * 4);
      const float vv[4] = {v.x, v.y, v.z, v.w};
#pragma unroll
      for (int u = 0; u < 4; ++u) {
        const float val = vv[u];
        const int e = e4 * 4 + u;
        if (val > b0) {
          b1 = b0; i1 = i0;
          b0 = val; i0 = e;
        } else if (val > b1) {
          b1 = val; i1 = e;
        }
      }
    }
    const float e1  = expf(b1 - b0);   // <= 1
    const float inv = 1.f / (1.f + e1);
    const int tok = m0 + tid;
    out_probs[tok * 2 + 0] = inv;
    out_probs[tok * 2 + 1] = e1 * inv;
    out_idx[tok * 2 + 0] = (float)i0;
    out_idx[tok * 2 + 1] = (float)i1;
  }
}

extern "C" void kernel_launch(void* const* d_in, const int* in_sizes, int n_in,
                              void* d_out, int out_size, void* d_ws, size_t ws_size,
                              hipStream_t stream) {
  const float* x = (const float*)d_in[0];
  const float* W = (const float*)d_in[1];

  const int E = 64;
  const int D = in_sizes[1] / E;            // 4096
  const int nTok = in_sizes[0] / D;         // 16384

  float* probs = (float*)d_out;                       // nTok*2 floats
  float* idxo  = (float*)d_out + (size_t)nTok * 2;    // nTok*2 "float" indices

  dim3 grid(nTok / TOKB), block(THREADS);
  hipLaunchKernelGGL(router_main, grid, block, 0, stream,
                     x, W, probs, idxo, D);
}

// Round 5
// 556.907 us; speedup vs baseline: 1.2053x; 1.2053x over previous
//
#include <hip/hip_runtime.h>
#include <math.h>

// TopK router: logits = x @ W^T (fp32), top-2 per token + softmax over the 2.
// x: [nTok, D] fp32, W: [E=64, D] fp32.
// out: [probs (nTok*2 f32)] ++ [idx (nTok*2, written as f32 values)]
//
// Structure: block = 8 waves (512 thr) over 64 tokens; lane = token.
// Experts split across waves (8 each, acc[8] -> no spill), K NOT split
// (each wave computes full dot products -> no cross-wave reduction).
// x staged per 64-k chunk into double-buffered LDS (stride 68: bank-free),
// read 8x via ds_read_b128. W loads are wave-uniform, 1-line TCP lookups,
// L1/L2-hot (W = 1 MB), with per-chunk hoisted base addresses + imm offsets.

typedef float f32x4 __attribute__((ext_vector_type(4)));

#define NW 8
#define TOK 64
#define EW 8          // experts per wave
#define CK 64         // staged k per chunk
#define LDT 68        // LDS row stride in floats (8 banks x 2-way = free)
#define THREADS (NW * 64)

__global__ __launch_bounds__(THREADS, 2)
void router_main(const float* __restrict__ x, const float* __restrict__ W,
                 float* __restrict__ out_probs, float* __restrict__ out_idx,
                 int D) {
  __shared__ float As[2][TOK][LDT];   // 2 * 64 * 68 * 4 = 34816 B

  const int tid  = threadIdx.x;
  const int w    = tid >> 6;      // wave id -> expert group
  const int lane = tid & 63;      // token within block
  const int m0   = blockIdx.x * TOK;
  const int nCh  = D / CK;        // 64 chunks

  const float* xrow  = x + (size_t)(m0 + lane) * D;   // this lane's token row
  const float* wbase = W + (size_t)(w * EW) * D;      // wave's expert slice

  float acc[EW];
#pragma unroll
  for (int e = 0; e < EW; ++e) acc[e] = 0.f;

  // prologue: stage chunk 0 (wave w stages col-blocks w and w+8)
  {
    const f32x4 a = *reinterpret_cast<const f32x4*>(xrow + 4 * w);
    const f32x4 b = *reinterpret_cast<const f32x4*>(xrow + 4 * (w + 8));
    *reinterpret_cast<f32x4*>(&As[0][lane][4 * w]) = a;
    *reinterpret_cast<f32x4*>(&As[0][lane][4 * (w + 8)]) = b;
  }
  __syncthreads();

  for (int c = 0; c < nCh; ++c) {
    const int buf = c & 1;

    // issue next chunk's global loads early (hide HBM latency under compute)
    f32x4 na, nb;
    const bool more = (c + 1 < nCh);
    if (more) {
      const float* xn = xrow + (size_t)(c + 1) * CK;
      na = *reinterpret_cast<const f32x4*>(xn + 4 * w);
      nb = *reinterpret_cast<const f32x4*>(xn + 4 * (w + 8));
    }

    // compute: 16 steps x (1 ds_read_b128 + 8 uniform W loads + 32 FMA)
    const float* wp = wbase + (size_t)c * CK;
#pragma unroll 4
    for (int kk = 0; kk < CK / 4; ++kk) {
      const f32x4 xv = *reinterpret_cast<const f32x4*>(&As[buf][lane][kk * 4]);
#pragma unroll
      for (int e = 0; e < EW; ++e) {
        const f32x4 wv =
            *reinterpret_cast<const f32x4*>(wp + (size_t)e * D + kk * 4);
        acc[e] = fmaf(xv.x, wv.x, acc[e]);
        acc[e] = fmaf(xv.y, wv.y, acc[e]);
        acc[e] = fmaf(xv.z, wv.z, acc[e]);
        acc[e] = fmaf(xv.w, wv.w, acc[e]);
      }
    }

    __syncthreads();                 // all waves done reading As[buf]
    if (more) {
      *reinterpret_cast<f32x4*>(&As[buf ^ 1][lane][4 * w]) = na;
      *reinterpret_cast<f32x4*>(&As[buf ^ 1][lane][4 * (w + 8)]) = nb;
    }
    __syncthreads();                 // next buffer published
  }

  // ---- logits to LDS (disjoint expert slices -> no reduction needed) ----
  float* L = &As[0][0][0];           // reuse staging memory: [64][68]
  *reinterpret_cast<f32x4*>(&L[lane * LDT + w * EW + 0]) =
      (f32x4){acc[0], acc[1], acc[2], acc[3]};
  *reinterpret_cast<f32x4*>(&L[lane * LDT + w * EW + 4]) =
      (f32x4){acc[4], acc[5], acc[6], acc[7]};
  __syncthreads();

  // ---- top-2 + softmax: one thread per token ----
  // Strict '>' keeps the lowest index on ties (jax.lax.top_k semantics).
  if (tid < TOK) {
    const float* row = &L[tid * LDT];
    float b0 = -INFINITY, b1 = -INFINITY;
    int i0 = 0, i1 = 0;
#pragma unroll
    for (int e4 = 0; e4 < 16; ++e4) {
      const f32x4 v = *reinterpret_cast<const f32x4*>(row + e4 * 4);
      const float vv[4] = {v.x, v.y, v.z, v.w};
#pragma unroll
      for (int u = 0; u < 4; ++u) {
        const float val = vv[u];
        const int e = e4 * 4 + u;
        if (val > b0) {
          b1 = b0; i1 = i0;
          b0 = val; i0 = e;
        } else if (val > b1) {
          b1 = val; i1 = e;
        }
      }
    }
    const float e1  = expf(b1 - b0);   // <= 1
    const float inv = 1.f / (1.f + e1);
    const int tok = m0 + tid;
    out_probs[tok * 2 + 0] = inv;
    out_probs[tok * 2 + 1] = e1 * inv;
    out_idx[tok * 2 + 0] = (float)i0;
    out_idx[tok * 2 + 1] = (float)i1;
  }
}

extern "C" void kernel_launch(void* const* d_in, const int* in_sizes, int n_in,
                              void* d_out, int out_size, void* d_ws, size_t ws_size,
                              hipStream_t stream) {
  const float* x = (const float*)d_in[0];
  const float* W = (const float*)d_in[1];

  const int E = 64;
  const int D = in_sizes[1] / E;            // 4096
  const int nTok = in_sizes[0] / D;         // 16384

  float* probs = (float*)d_out;                       // nTok*2 floats
  float* idxo  = (float*)d_out + (size_t)nTok * 2;    // nTok*2 "float" indices

  dim3 grid(nTok / TOK), block(THREADS);
  hipLaunchKernelGGL(router_main, grid, block, 0, stream,
                     x, W, probs, idxo, D);
}

// Round 6
// 411.651 us; speedup vs baseline: 1.6306x; 1.3529x over previous
//
#include <hip/hip_runtime.h>
#include <math.h>

// TopK router: logits = x @ W^T (fp32), top-2 per token + softmax over the 2.
// x: [nTok, D] fp32, W: [E=64, D] fp32.
// out: [probs (nTok*2 f32)] ++ [idx (nTok*2, written as f32 values)]
//
// Structure: block = 8 waves (512 thr) over 64 tokens; lane = token.
// Experts split across waves (8 each, acc[8] -> no spill), K NOT split.
// x staged per 64-k chunk into double-buffered LDS (stride 68: bank-free),
// read via ds_read_b128. W addresses are readfirstlane-uniform -> compiler
// scalarizes to s_load (SMEM/constant-cache pipe, off TCP and VALU);
// v_fmac_f32 takes the W value as its one legal SGPR operand.

typedef float f32x4 __attribute__((ext_vector_type(4)));

#define NW 8
#define TOK 64
#define EW 8          // experts per wave
#define CK 64         // staged k per chunk
#define LDT 68        // LDS row stride in floats (8 banks x 2-way = free)
#define THREADS (NW * 64)

__global__ __launch_bounds__(THREADS, 2)
void router_main(const float* __restrict__ x, const float* __restrict__ W,
                 float* __restrict__ out_probs, float* __restrict__ out_idx,
                 int D) {
  __shared__ float As[2][TOK][LDT];   // 2 * 64 * 68 * 4 = 34816 B

  const int tid  = threadIdx.x;
  // readfirstlane => wave id is an SGPR value; W addressing below is then
  // provably uniform -> s_load scalarization (round-2 evidence: SGPR=112).
  const int w    = __builtin_amdgcn_readfirstlane(tid >> 6);
  const int lane = tid & 63;      // token within block
  const int m0   = blockIdx.x * TOK;
  const int nCh  = D / CK;        // 64 chunks

  const float* xrow  = x + (size_t)(m0 + lane) * D;   // this lane's token row
  const float* __restrict__ wbase = W + (size_t)(w * EW) * D;  // expert slice

  float acc[EW];
#pragma unroll
  for (int e = 0; e < EW; ++e) acc[e] = 0.f;

  // prologue: stage chunk 0 (wave w stages col-blocks w and w+8)
  {
    const f32x4 a = *reinterpret_cast<const f32x4*>(xrow + 4 * w);
    const f32x4 b = *reinterpret_cast<const f32x4*>(xrow + 4 * (w + 8));
    *reinterpret_cast<f32x4*>(&As[0][lane][4 * w]) = a;
    *reinterpret_cast<f32x4*>(&As[0][lane][4 * (w + 8)]) = b;
  }
  __syncthreads();

  for (int c = 0; c < nCh; ++c) {
    const int buf = c & 1;

    // issue next chunk's global loads early (hide HBM latency under compute)
    f32x4 na, nb;
    const bool more = (c + 1 < nCh);
    if (more) {
      const float* xn = xrow + (size_t)(c + 1) * CK;
      na = *reinterpret_cast<const f32x4*>(xn + 4 * w);
      nb = *reinterpret_cast<const f32x4*>(xn + 4 * (w + 8));
    }

    // compute: 16 steps x (1 ds_read_b128 + 8 scalar W loads + 32 FMA)
    const float* __restrict__ wp = wbase + (size_t)c * CK;
#pragma unroll 4
    for (int kk = 0; kk < CK / 4; ++kk) {
      const f32x4 xv = *reinterpret_cast<const f32x4*>(&As[buf][lane][kk * 4]);
#pragma unroll
      for (int e = 0; e < EW; ++e) {
        const f32x4 wv =
            *reinterpret_cast<const f32x4*>(wp + (size_t)e * D + kk * 4);
        acc[e] = fmaf(xv.x, wv.x, acc[e]);
        acc[e] = fmaf(xv.y, wv.y, acc[e]);
        acc[e] = fmaf(xv.z, wv.z, acc[e]);
        acc[e] = fmaf(xv.w, wv.w, acc[e]);
      }
    }

    __syncthreads();                 // all waves done reading As[buf]
    if (more) {
      *reinterpret_cast<f32x4*>(&As[buf ^ 1][lane][4 * w]) = na;
      *reinterpret_cast<f32x4*>(&As[buf ^ 1][lane][4 * (w + 8)]) = nb;
    }
    __syncthreads();                 // next buffer published
  }

  // ---- logits to LDS (disjoint expert slices -> no reduction needed) ----
  float* L = &As[0][0][0];           // reuse staging memory: [64][68]
  *reinterpret_cast<f32x4*>(&L[lane * LDT + w * EW + 0]) =
      (f32x4){acc[0], acc[1], acc[2], acc[3]};
  *reinterpret_cast<f32x4*>(&L[lane * LDT + w * EW + 4]) =
      (f32x4){acc[4], acc[5], acc[6], acc[7]};
  __syncthreads();

  // ---- top-2 + softmax: one thread per token ----
  // Strict '>' keeps the lowest index on ties (jax.lax.top_k semantics).
  if (tid < TOK) {
    const float* row = &L[tid * LDT];
    float b0 = -INFINITY, b1 = -INFINITY;
    int i0 = 0, i1 = 0;
#pragma unroll
    for (int e4 = 0; e4 < 16; ++e4) {
      const f32x4 v = *reinterpret_cast<const f32x4*>(row + e4 * 4);
      const float vv[4] = {v.x, v.y, v.z, v.w};
#pragma unroll
      for (int u = 0; u < 4; ++u) {
        const float val = vv[u];
        const int e = e4 * 4 + u;
        if (val > b0) {
          b1 = b0; i1 = i0;
          b0 = val; i0 = e;
        } else if (val > b1) {
          b1 = val; i1 = e;
        }
      }
    }
    const float e1  = expf(b1 - b0);   // <= 1
    const float inv = 1.f / (1.f + e1);
    const int tok = m0 + tid;
    out_probs[tok * 2 + 0] = inv;
    out_probs[tok * 2 + 1] = e1 * inv;
    out_idx[tok * 2 + 0] = (float)i0;
    out_idx[tok * 2 + 1] = (float)i1;
  }
}

extern "C" void kernel_launch(void* const* d_in, const int* in_sizes, int n_in,
                              void* d_out, int out_size, void* d_ws, size_t ws_size,
                              hipStream_t stream) {
  const float* x = (const float*)d_in[0];
  const float* W = (const float*)d_in[1];

  const int E = 64;
  const int D = in_sizes[1] / E;            // 4096
  const int nTok = in_sizes[0] / D;         // 16384

  float* probs = (float*)d_out;                       // nTok*2 floats
  float* idxo  = (float*)d_out + (size_t)nTok * 2;    // nTok*2 "float" indices

  dim3 grid(nTok / TOK), block(THREADS);
  hipLaunchKernelGGL(router_main, grid, block, 0, stream,
                     x, W, probs, idxo, D);
}

// Round 7
// 242.262 us; speedup vs baseline: 2.7707x; 1.6992x over previous
//
#include <hip/hip_runtime.h>
#include <math.h>

// TopK router: logits = x @ W^T (fp32), top-2 per token + softmax over the 2.
// x: [nTok, D] fp32, W: [E=64, D] fp32.
// out: [probs (nTok*2 f32)] ++ [idx (nTok*2, written as f32 values)]
//
// Round-7 structure: K split across KS blocks (grid = 256*KS). Each block =
// 8 waves over 64 tokens (lane = token), 8 experts/wave (acc[8]), covers
// D/KS of K; writes a 64x64 partial-logit tile to d_ws [bid][e][t].
// 4 co-resident blocks/CU (LDS 139KB, VGPR<=64) bury the lgkmcnt(0)
// s_load latency that capped per-wave VALU duty at ~21% in rounds 5/6.
// Kernel 2 sums the KS slices in fixed k-order and does top-2 + softmax.

typedef float f32x4 __attribute__((ext_vector_type(4)));

#define NW 8
#define TOK 64
#define EW 8          // experts per wave
#define CK 64         // staged k per chunk
#define LDT 68        // LDS row stride in floats (8 banks x 2-way = free)
#define THREADS (NW * 64)
#define NE 64

__global__ __launch_bounds__(THREADS, 8)
void router_partial(const float* __restrict__ x, const float* __restrict__ W,
                    float* __restrict__ part, int D, int ksLog2) {
  __shared__ float As[2][TOK][LDT];   // 34816 B -> 4 blocks/CU fit in 160KB

  const int tid  = threadIdx.x;
  // readfirstlane => provably uniform W addressing -> s_load scalarization
  const int w    = __builtin_amdgcn_readfirstlane(tid >> 6);
  const int lane = tid & 63;        // token within block
  const int bid  = blockIdx.x;
  const int tb   = bid >> ksLog2;   // token block
  const int s    = bid & ((1 << ksLog2) - 1);   // k-slice
  const int m0   = tb * TOK;
  const int Ks   = D >> ksLog2;     // k per slice
  const int nCh  = Ks / CK;
  const int k0   = s * Ks;

  const float* xrow = x + (size_t)(m0 + lane) * D + k0;
  const float* __restrict__ wbase = W + (size_t)(w * EW) * D + k0;

  float acc[EW];
#pragma unroll
  for (int e = 0; e < EW; ++e) acc[e] = 0.f;

  // prologue: stage chunk 0 (wave w stages f4-cols w and w+8)
  {
    const f32x4 a = *reinterpret_cast<const f32x4*>(xrow + 4 * w);
    const f32x4 b = *reinterpret_cast<const f32x4*>(xrow + 4 * (w + 8));
    *reinterpret_cast<f32x4*>(&As[0][lane][4 * w]) = a;
    *reinterpret_cast<f32x4*>(&As[0][lane][4 * (w + 8)]) = b;
  }
  __syncthreads();

  for (int c = 0; c < nCh; ++c) {
    const int buf = c & 1;

    // issue next chunk's x loads early (hide HBM latency under compute)
    f32x4 na, nb;
    const bool more = (c + 1 < nCh);
    if (more) {
      const float* xn = xrow + (size_t)(c + 1) * CK;
      na = *reinterpret_cast<const f32x4*>(xn + 4 * w);
      nb = *reinterpret_cast<const f32x4*>(xn + 4 * (w + 8));
    }

    // compute: 16 steps x (1 ds_read_b128 + 8 scalar W loads + 32 FMA)
    // unroll 2 keeps live W SGPRs ~64 (SGPR file is the occupancy limiter)
    const float* __restrict__ wp = wbase + (size_t)c * CK;
#pragma unroll 2
    for (int kk = 0; kk < CK / 4; ++kk) {
      const f32x4 xv = *reinterpret_cast<const f32x4*>(&As[buf][lane][kk * 4]);
#pragma unroll
      for (int e = 0; e < EW; ++e) {
        const f32x4 wv =
            *reinterpret_cast<const f32x4*>(wp + (size_t)e * D + kk * 4);
        acc[e] = fmaf(xv.x, wv.x, acc[e]);
        acc[e] = fmaf(xv.y, wv.y, acc[e]);
        acc[e] = fmaf(xv.z, wv.z, acc[e]);
        acc[e] = fmaf(xv.w, wv.w, acc[e]);
      }
    }

    __syncthreads();                 // all waves done reading As[buf]
    if (more) {
      *reinterpret_cast<f32x4*>(&As[buf ^ 1][lane][4 * w]) = na;
      *reinterpret_cast<f32x4*>(&As[buf ^ 1][lane][4 * (w + 8)]) = nb;
    }
    __syncthreads();                 // next buffer published
  }

  // partials -> ws at [bid][e][t] (per j: 64 lanes x 4B contiguous = coalesced)
  float* pb = part + (size_t)bid * (NE * TOK) + (size_t)(w * EW) * TOK + lane;
#pragma unroll
  for (int j = 0; j < EW; ++j) pb[j * TOK] = acc[j];
}

__global__ __launch_bounds__(64)
void router_reduce(const float* __restrict__ part,
                   float* __restrict__ out_probs, float* __restrict__ out_idx,
                   int KS) {
  const int tb = blockIdx.x;
  const int t  = threadIdx.x;       // token within block
  const float* pb = part + (size_t)tb * KS * (NE * TOK) + t;

  // sum slices in ascending k order (deterministic), strict-'>' top-2
  // (lowest index wins ties = jax.lax.top_k semantics)
  float b0 = -INFINITY, b1 = -INFINITY;
  int i0 = 0, i1 = 0;
  for (int e = 0; e < NE; ++e) {
    float v = pb[e * TOK];
    for (int s = 1; s < KS; ++s) v += pb[(size_t)s * (NE * TOK) + e * TOK];
    if (v > b0) {
      b1 = b0; i1 = i0;
      b0 = v;  i0 = e;
    } else if (v > b1) {
      b1 = v; i1 = e;
    }
  }
  const float e1  = expf(b1 - b0);   // <= 1
  const float inv = 1.f / (1.f + e1);
  const int tok = tb * TOK + t;
  out_probs[tok * 2 + 0] = inv;
  out_probs[tok * 2 + 1] = e1 * inv;
  out_idx[tok * 2 + 0] = (float)i0;
  out_idx[tok * 2 + 1] = (float)i1;
}

// ---- fused fallback (round-6 kernel) for the ws_size < 4MB case ----
__global__ __launch_bounds__(THREADS, 2)
void router_fused(const float* __restrict__ x, const float* __restrict__ W,
                  float* __restrict__ out_probs, float* __restrict__ out_idx,
                  int D) {
  __shared__ float As[2][TOK][LDT];

  const int tid  = threadIdx.x;
  const int w    = __builtin_amdgcn_readfirstlane(tid >> 6);
  const int lane = tid & 63;
  const int m0   = blockIdx.x * TOK;
  const int nCh  = D / CK;

  const float* xrow  = x + (size_t)(m0 + lane) * D;
  const float* __restrict__ wbase = W + (size_t)(w * EW) * D;

  float acc[EW];
#pragma unroll
  for (int e = 0; e < EW; ++e) acc[e] = 0.f;

  {
    const f32x4 a = *reinterpret_cast<const f32x4*>(xrow + 4 * w);
    const f32x4 b = *reinterpret_cast<const f32x4*>(xrow + 4 * (w + 8));
    *reinterpret_cast<f32x4*>(&As[0][lane][4 * w]) = a;
    *reinterpret_cast<f32x4*>(&As[0][lane][4 * (w + 8)]) = b;
  }
  __syncthreads();

  for (int c = 0; c < nCh; ++c) {
    const int buf = c & 1;
    f32x4 na, nb;
    const bool more = (c + 1 < nCh);
    if (more) {
      const float* xn = xrow + (size_t)(c + 1) * CK;
      na = *reinterpret_cast<const f32x4*>(xn + 4 * w);
      nb = *reinterpret_cast<const f32x4*>(xn + 4 * (w + 8));
    }
    const float* __restrict__ wp = wbase + (size_t)c * CK;
#pragma unroll 2
    for (int kk = 0; kk < CK / 4; ++kk) {
      const f32x4 xv = *reinterpret_cast<const f32x4*>(&As[buf][lane][kk * 4]);
#pragma unroll
      for (int e = 0; e < EW; ++e) {
        const f32x4 wv =
            *reinterpret_cast<const f32x4*>(wp + (size_t)e * D + kk * 4);
        acc[e] = fmaf(xv.x, wv.x, acc[e]);
        acc[e] = fmaf(xv.y, wv.y, acc[e]);
        acc[e] = fmaf(xv.z, wv.z, acc[e]);
        acc[e] = fmaf(xv.w, wv.w, acc[e]);
      }
    }
    __syncthreads();
    if (more) {
      *reinterpret_cast<f32x4*>(&As[buf ^ 1][lane][4 * w]) = na;
      *reinterpret_cast<f32x4*>(&As[buf ^ 1][lane][4 * (w + 8)]) = nb;
    }
    __syncthreads();
  }

  float* L = &As[0][0][0];
  *reinterpret_cast<f32x4*>(&L[lane * LDT + w * EW + 0]) =
      (f32x4){acc[0], acc[1], acc[2], acc[3]};
  *reinterpret_cast<f32x4*>(&L[lane * LDT + w * EW + 4]) =
      (f32x4){acc[4], acc[5], acc[6], acc[7]};
  __syncthreads();

  if (tid < TOK) {
    const float* row = &L[tid * LDT];
    float b0 = -INFINITY, b1 = -INFINITY;
    int i0 = 0, i1 = 0;
#pragma unroll
    for (int e = 0; e < NE; ++e) {
      const float val = row[e];
      if (val > b0) {
        b1 = b0; i1 = i0;
        b0 = val; i0 = e;
      } else if (val > b1) {
        b1 = val; i1 = e;
      }
    }
    const float e1  = expf(b1 - b0);
    const float inv = 1.f / (1.f + e1);
    const int tok = m0 + tid;
    out_probs[tok * 2 + 0] = inv;
    out_probs[tok * 2 + 1] = e1 * inv;
    out_idx[tok * 2 + 0] = (float)i0;
    out_idx[tok * 2 + 1] = (float)i1;
  }
}

extern "C" void kernel_launch(void* const* d_in, const int* in_sizes, int n_in,
                              void* d_out, int out_size, void* d_ws, size_t ws_size,
                              hipStream_t stream) {
  const float* x = (const float*)d_in[0];
  const float* W = (const float*)d_in[1];

  const int E = 64;
  const int D = in_sizes[1] / E;            // 4096
  const int nTok = in_sizes[0] / D;         // 16384
  const int nTB  = nTok / TOK;              // 256 token blocks

  float* probs = (float*)d_out;                       // nTok*2 floats
  float* idxo  = (float*)d_out + (size_t)nTok * 2;    // nTok*2 "float" indices

  // partial buffer: (nTB * KS) * 64 * 64 floats = KS * 4 MB (nTok=16384)
  const size_t sliceBytes = (size_t)nTB * NE * TOK * sizeof(float);
  int ksLog2;
  if      (ws_size >= 4 * sliceBytes) ksLog2 = 2;
  else if (ws_size >= 2 * sliceBytes) ksLog2 = 1;
  else if (ws_size >= 1 * sliceBytes) ksLog2 = 0;
  else ksLog2 = -1;

  if (ksLog2 >= 0) {
    const int KS = 1 << ksLog2;
    float* part = (float*)d_ws;
    hipLaunchKernelGGL(router_partial, dim3(nTB * KS), dim3(THREADS), 0, stream,
                       x, W, part, D, ksLog2);
    hipLaunchKernelGGL(router_reduce, dim3(nTB), dim3(64), 0, stream,
                       part, probs, idxo, KS);
  } else {
    hipLaunchKernelGGL(router_fused, dim3(nTB), dim3(THREADS), 0, stream,
                       x, W, probs, idxo, D);
  }
}

// Round 8
// 124.174 us; speedup vs baseline: 5.4057x; 1.9510x over previous
//
#include <hip/hip_runtime.h>
#include <math.h>

// TopK router via split-bf16 MFMA: logits = x @ W^T, top-2 + softmax.
// x = xh + xl (bf16 RTNE split), W likewise (preconverted to ws).
// logits = xh*wh + xh*wl + xl*wh  (fp32 MFMA accumulate; dropped xl*wl
// term ~2^-18 relative = below fp32 sum-reorder noise).
//
// Main kernel: grid 256 (1 block/CU), 512 thr = 8 waves.
// Block = 64 tok x 64 exp x K4096. Chunk CK=128 k staged in 64KB LDS
// (Ah/Al/Bh/Bl, 16KB each, XOR-swizzled rows). Wave = (token-half, K32
// window): tile 32 tok x 64 exp = 2x4 MFMA tiles of 16x16x32, acc 32 VGPR.
// Epilogue: 4-way k-window reduce in LDS, decode C-layout, 64-thr top-2.

typedef float f32x4 __attribute__((ext_vector_type(4)));
typedef short bf16x8 __attribute__((ext_vector_type(8)));
typedef unsigned int u32;

#define NE 64
#define TOK 64
#define CK 128
#define THREADS 512
#define LDE 68

__device__ __forceinline__ u32 rtne_bf16(float f) {
  u32 u = __builtin_bit_cast(u32, f);
  return (u + 0x7FFFu + ((u >> 16) & 1u)) >> 16;
}
__device__ __forceinline__ float bf16_to_f(u32 h) {
  return __builtin_bit_cast(float, h << 16);
}
// LDS byte address: 256B rows (128 bf16), 16B block b XOR-swizzled by row
__device__ __forceinline__ int lds_addr(int base, int row, int blk, int off8) {
  return base + row * 256 + ((blk ^ (row & 7)) << 4) + off8;
}

__global__ __launch_bounds__(256)
void wprep(const float* __restrict__ Wg, uint2* __restrict__ Who,
           uint2* __restrict__ Wlo) {
  const int i = blockIdx.x * 256 + threadIdx.x;   // f32x4 index (65536 total)
  const f32x4 v = *((const f32x4*)Wg + i);
  const u32 h0 = rtne_bf16(v.x), h1 = rtne_bf16(v.y);
  const u32 h2 = rtne_bf16(v.z), h3 = rtne_bf16(v.w);
  const u32 l0 = rtne_bf16(v.x - bf16_to_f(h0));
  const u32 l1 = rtne_bf16(v.y - bf16_to_f(h1));
  const u32 l2 = rtne_bf16(v.z - bf16_to_f(h2));
  const u32 l3 = rtne_bf16(v.w - bf16_to_f(h3));
  Who[i] = make_uint2(h0 | (h1 << 16), h2 | (h3 << 16));
  Wlo[i] = make_uint2(l0 | (l1 << 16), l2 | (l3 << 16));
}

__global__ __launch_bounds__(THREADS)
void gemm_topk(const float* __restrict__ x, const u32* __restrict__ Whg,
               const u32* __restrict__ Wlg, float* __restrict__ out_probs,
               float* __restrict__ out_idx, int D) {
  __shared__ __align__(16) char smem[65536];
  // staging bases: Ah 0, Al 16K, Bh 32K, Bl 48K

  const int tid = threadIdx.x;
  const int w   = tid >> 6;
  const int l   = tid & 63;
  const int th  = w >> 2;          // token half (0/1)
  const int kw  = w & 3;           // K32 window within chunk
  const int m0  = blockIdx.x * TOK;
  const int nCh = D / CK;          // 32

  // x staging map: 4 passes, row=tid>>3, k4=(tid&7)+p*8 (f32x4 units)
  const int xr = tid >> 3, xc = tid & 7;
  // W staging map: 2 passes, idx=tid+p*512: row=idx>>4, blk=idx&15
  const int Du = D / 2;            // u32 per W row

  f32x4 acc[2][4];
#pragma unroll
  for (int m = 0; m < 2; ++m)
#pragma unroll
    for (int n = 0; n < 4; ++n) acc[m][n] = (f32x4){0.f, 0.f, 0.f, 0.f};

  const float* xg = x + (size_t)(m0 + xr) * D + xc * 4;

  f32x4 xv[4];
  uint4 whv[2], wlv[2];

  // prefetch chunk 0
#pragma unroll
  for (int p = 0; p < 4; ++p)
    xv[p] = __builtin_nontemporal_load((const f32x4*)(xg + p * 32));
#pragma unroll
  for (int p = 0; p < 2; ++p) {
    const int idx = tid + p * THREADS, row = idx >> 4, blk = idx & 15;
    whv[p] = *(const uint4*)(Whg + (size_t)row * Du + blk * 4);
    wlv[p] = *(const uint4*)(Wlg + (size_t)row * Du + blk * 4);
  }

  for (int c = 0; c < nCh; ++c) {
    // convert x regs -> bf16 h/l packs
    uint2 xh[4], xl[4];
#pragma unroll
    for (int p = 0; p < 4; ++p) {
      const f32x4 v = xv[p];
      const u32 h0 = rtne_bf16(v.x), h1 = rtne_bf16(v.y);
      const u32 h2 = rtne_bf16(v.z), h3 = rtne_bf16(v.w);
      xh[p] = make_uint2(h0 | (h1 << 16), h2 | (h3 << 16));
      const u32 l0 = rtne_bf16(v.x - bf16_to_f(h0));
      const u32 l1 = rtne_bf16(v.y - bf16_to_f(h1));
      const u32 l2 = rtne_bf16(v.z - bf16_to_f(h2));
      const u32 l3 = rtne_bf16(v.w - bf16_to_f(h3));
      xl[p] = make_uint2(l0 | (l1 << 16), l2 | (l3 << 16));
    }

    __syncthreads();   // previous chunk's reads complete -> LDS writable
#pragma unroll
    for (int p = 0; p < 4; ++p) {
      const int k4 = xc + p * 8;                 // f32x4 unit in row
      const int blk = k4 >> 1, off8 = (k4 & 1) * 8;
      *(uint2*)(smem + lds_addr(0,     xr, blk, off8)) = xh[p];
      *(uint2*)(smem + lds_addr(16384, xr, blk, off8)) = xl[p];
    }
#pragma unroll
    for (int p = 0; p < 2; ++p) {
      const int idx = tid + p * THREADS, row = idx >> 4, blk = idx & 15;
      *(uint4*)(smem + lds_addr(32768, row, blk, 0)) = whv[p];
      *(uint4*)(smem + lds_addr(49152, row, blk, 0)) = wlv[p];
    }
    __syncthreads();   // chunk c visible

    // issue next chunk's global loads (fly under compute)
    if (c + 1 < nCh) {
      const float* xn = xg + (size_t)(c + 1) * CK;
#pragma unroll
      for (int p = 0; p < 4; ++p)
        xv[p] = __builtin_nontemporal_load((const f32x4*)(xn + p * 32));
#pragma unroll
      for (int p = 0; p < 2; ++p) {
        const int idx = tid + p * THREADS, row = idx >> 4, blk = idx & 15;
        whv[p] = *(const uint4*)(Whg + (size_t)row * Du + (c + 1) * (CK / 2) + blk * 4);
        wlv[p] = *(const uint4*)(Wlg + (size_t)row * Du + (c + 1) * (CK / 2) + blk * 4);
      }
    }

    // compute: my K32 window on my token half
    const int g = l >> 4, r16 = l & 15;
    const int blk = kw * 4 + g;
    bf16x8 ah[2], al_[2], bh[4], bl_[4];
#pragma unroll
    for (int m = 0; m < 2; ++m) {
      const int row = th * 32 + m * 16 + r16;
      ah[m]  = *(const bf16x8*)(smem + lds_addr(0,     row, blk, 0));
      al_[m] = *(const bf16x8*)(smem + lds_addr(16384, row, blk, 0));
    }
#pragma unroll
    for (int n = 0; n < 4; ++n) {
      const int row = n * 16 + r16;
      bh[n]  = *(const bf16x8*)(smem + lds_addr(32768, row, blk, 0));
      bl_[n] = *(const bf16x8*)(smem + lds_addr(49152, row, blk, 0));
    }
#pragma unroll
    for (int m = 0; m < 2; ++m)
#pragma unroll
      for (int n = 0; n < 4; ++n) {
        acc[m][n] = __builtin_amdgcn_mfma_f32_16x16x32_bf16(ah[m],  bh[n],  acc[m][n], 0, 0, 0);
        acc[m][n] = __builtin_amdgcn_mfma_f32_16x16x32_bf16(ah[m],  bl_[n], acc[m][n], 0, 0, 0);
        acc[m][n] = __builtin_amdgcn_mfma_f32_16x16x32_bf16(al_[m], bh[n],  acc[m][n], 0, 0, 0);
      }
  }

  // ---- epilogue: reduce 4 k-windows, decode, top-2 ----
  __syncthreads();                  // all staged reads done
  float* R = (float*)smem;          // [8 waves][32 tr][64 lanes]
#pragma unroll
  for (int m = 0; m < 2; ++m)
#pragma unroll
    for (int n = 0; n < 4; ++n)
#pragma unroll
      for (int r = 0; r < 4; ++r)
        R[w * 2048 + ((m * 4 + n) * 4 + r) * 64 + l] = acc[m][n][r];
  __syncthreads();

  float vals[8];
  int dsti[8];
#pragma unroll
  for (int i = 0; i < 8; ++i) {
    const int j  = tid + i * THREADS;
    const int hh = j >> 11, rem = j & 2047;
    const int tr = rem >> 6, ll = rem & 63;
    float v = R[(hh * 4 + 0) * 2048 + tr * 64 + ll];
    v      += R[(hh * 4 + 1) * 2048 + tr * 64 + ll];
    v      += R[(hh * 4 + 2) * 2048 + tr * 64 + ll];
    v      += R[(hh * 4 + 3) * 2048 + tr * 64 + ll];
    const int tile = tr >> 2, rr = tr & 3, mm = tile >> 2, nn = tile & 3;
    const int token = hh * 32 + mm * 16 + ((ll >> 4) << 2) + rr;
    const int expi  = nn * 16 + (ll & 15);
    vals[i] = v;
    dsti[i] = token * LDE + expi;
  }
  __syncthreads();                  // reads done before aliasing writes
  float* Lf = (float*)smem;         // [64][68]
#pragma unroll
  for (int i = 0; i < 8; ++i) Lf[dsti[i]] = vals[i];
  __syncthreads();

  if (tid < TOK) {
    const float* row = &Lf[tid * LDE];
    float b0 = -INFINITY, b1 = -INFINITY;
    int i0 = 0, i1 = 0;
#pragma unroll
    for (int e = 0; e < NE; ++e) {   // strict '>' = lowest index on ties
      const float val = row[e];
      if (val > b0) { b1 = b0; i1 = i0; b0 = val; i0 = e; }
      else if (val > b1) { b1 = val; i1 = e; }
    }
    const float e1  = expf(b1 - b0);
    const float inv = 1.f / (1.f + e1);
    const int tok = m0 + tid;
    out_probs[tok * 2 + 0] = inv;
    out_probs[tok * 2 + 1] = e1 * inv;
    out_idx[tok * 2 + 0] = (float)i0;
    out_idx[tok * 2 + 1] = (float)i1;
  }
}

// ---- fallback (round-6 fused VALU kernel) if ws is too small ----
typedef float f32x4b __attribute__((ext_vector_type(4)));
#define FEW 8
#define FCK 64
#define FLDT 68
__global__ __launch_bounds__(512, 2)
void router_fused(const float* __restrict__ x, const float* __restrict__ W,
                  float* __restrict__ out_probs, float* __restrict__ out_idx,
                  int D) {
  __shared__ float As[2][TOK][FLDT];
  const int tid = threadIdx.x;
  const int w = __builtin_amdgcn_readfirstlane(tid >> 6);
  const int lane = tid & 63;
  const int m0 = blockIdx.x * TOK;
  const int nCh = D / FCK;
  const float* xrow = x + (size_t)(m0 + lane) * D;
  const float* __restrict__ wbase = W + (size_t)(w * FEW) * D;
  float acc[FEW];
#pragma unroll
  for (int e = 0; e < FEW; ++e) acc[e] = 0.f;
  {
    const f32x4b a = *reinterpret_cast<const f32x4b*>(xrow + 4 * w);
    const f32x4b b = *reinterpret_cast<const f32x4b*>(xrow + 4 * (w + 8));
    *reinterpret_cast<f32x4b*>(&As[0][lane][4 * w]) = a;
    *reinterpret_cast<f32x4b*>(&As[0][lane][4 * (w + 8)]) = b;
  }
  __syncthreads();
  for (int c = 0; c < nCh; ++c) {
    const int buf = c & 1;
    f32x4b na, nb;
    const bool more = (c + 1 < nCh);
    if (more) {
      const float* xn = xrow + (size_t)(c + 1) * FCK;
      na = *reinterpret_cast<const f32x4b*>(xn + 4 * w);
      nb = *reinterpret_cast<const f32x4b*>(xn + 4 * (w + 8));
    }
    const float* __restrict__ wp = wbase + (size_t)c * FCK;
#pragma unroll 2
    for (int kk = 0; kk < FCK / 4; ++kk) {
      const f32x4b xvv = *reinterpret_cast<const f32x4b*>(&As[buf][lane][kk * 4]);
#pragma unroll
      for (int e = 0; e < FEW; ++e) {
        const f32x4b wv = *reinterpret_cast<const f32x4b*>(wp + (size_t)e * D + kk * 4);
        acc[e] = fmaf(xvv.x, wv.x, acc[e]);
        acc[e] = fmaf(xvv.y, wv.y, acc[e]);
        acc[e] = fmaf(xvv.z, wv.z, acc[e]);
        acc[e] = fmaf(xvv.w, wv.w, acc[e]);
      }
    }
    __syncthreads();
    if (more) {
      *reinterpret_cast<f32x4b*>(&As[buf ^ 1][lane][4 * w]) = na;
      *reinterpret_cast<f32x4b*>(&As[buf ^ 1][lane][4 * (w + 8)]) = nb;
    }
    __syncthreads();
  }
  float* L = &As[0][0][0];
  *reinterpret_cast<f32x4b*>(&L[lane * FLDT + w * FEW + 0]) =
      (f32x4b){acc[0], acc[1], acc[2], acc[3]};
  *reinterpret_cast<f32x4b*>(&L[lane * FLDT + w * FEW + 4]) =
      (f32x4b){acc[4], acc[5], acc[6], acc[7]};
  __syncthreads();
  if (tid < TOK) {
    const float* row = &L[tid * FLDT];
    float b0 = -INFINITY, b1 = -INFINITY;
    int i0 = 0, i1 = 0;
#pragma unroll
    for (int e = 0; e < NE; ++e) {
      const float val = row[e];
      if (val > b0) { b1 = b0; i1 = i0; b0 = val; i0 = e; }
      else if (val > b1) { b1 = val; i1 = e; }
    }
    const float e1 = expf(b1 - b0);
    const float inv = 1.f / (1.f + e1);
    const int tok = m0 + tid;
    out_probs[tok * 2 + 0] = inv;
    out_probs[tok * 2 + 1] = e1 * inv;
    out_idx[tok * 2 + 0] = (float)i0;
    out_idx[tok * 2 + 1] = (float)i1;
  }
}

extern "C" void kernel_launch(void* const* d_in, const int* in_sizes, int n_in,
                              void* d_out, int out_size, void* d_ws, size_t ws_size,
                              hipStream_t stream) {
  const float* x = (const float*)d_in[0];
  const float* W = (const float*)d_in[1];

  const int E = 64;
  const int D = in_sizes[1] / E;            // 4096
  const int nTok = in_sizes[0] / D;         // 16384
  const int nTB  = nTok / TOK;              // 256

  float* probs = (float*)d_out;
  float* idxo  = (float*)d_out + (size_t)nTok * 2;

  const size_t wBytes = (size_t)E * D * sizeof(short);   // 512 KB per half
  if (ws_size >= 2 * wBytes) {
    u32* Wh = (u32*)d_ws;
    u32* Wl = (u32*)((char*)d_ws + wBytes);
    hipLaunchKernelGGL(wprep, dim3((E * D / 4) / 256), dim3(256), 0, stream,
                       W, (uint2*)Wh, (uint2*)Wl);
    hipLaunchKernelGGL(gemm_topk, dim3(nTB), dim3(THREADS), 0, stream,
                       x, Wh, Wl, probs, idxo, D);
  } else {
    hipLaunchKernelGGL(router_fused, dim3(nTB), dim3(512), 0, stream,
                       x, W, probs, idxo, D);
  }
}

// Round 9
// 109.845 us; speedup vs baseline: 6.1108x; 1.1304x over previous
//
#include <hip/hip_runtime.h>
#include <math.h>

// TopK router via split-bf16 MFMA: logits = x @ W^T, top-2 + softmax.
// x = xh + xl (bf16 RTNE split), W likewise (preconverted to ws by wprep).
// logits = xh*wh + xh*wl + xl*wh (fp32 MFMA accumulate).
//
// Round-9 structure: grid 512 (2 blocks/CU), 512 thr = 8 waves, 32 tok/block.
// A (x) staged to double-buffered swizzled LDS (16KB/buf), ONE barrier/chunk.
// B (W h/l bf16) read directly from global per fragment -> L2-hot, no LDS.
// Wave = (kw k-window 0..3, eh expert-half 0..1): 2x2 MFMA tiles 16x16x32,
// acc 16 VGPR. Epilogue: kw-reduce via LDS, decode C layout, 32-thr top-2.

typedef float f32x4 __attribute__((ext_vector_type(4)));
typedef short bf16x8 __attribute__((ext_vector_type(8)));
typedef unsigned int u32;

#define NE 64
#define TOK 32
#define CK 128
#define THREADS 512
#define LDE 68

__device__ __forceinline__ u32 rtne_bf16(float f) {
  u32 u = __builtin_bit_cast(u32, f);
  return (u + 0x7FFFu + ((u >> 16) & 1u)) >> 16;
}
__device__ __forceinline__ float bf16_to_f(u32 h) {
  return __builtin_bit_cast(float, h << 16);
}
// LDS byte address: 256B rows (128 bf16), 16B block XOR-swizzled by row
__device__ __forceinline__ int lds_addr(int base, int row, int blk) {
  return base + row * 256 + ((blk ^ (row & 7)) << 4);
}

__global__ __launch_bounds__(256)
void wprep(const float* __restrict__ Wg, uint2* __restrict__ Who,
           uint2* __restrict__ Wlo) {
  const int i = blockIdx.x * 256 + threadIdx.x;   // f32x4 index (65536 total)
  const f32x4 v = *((const f32x4*)Wg + i);
  const u32 h0 = rtne_bf16(v.x), h1 = rtne_bf16(v.y);
  const u32 h2 = rtne_bf16(v.z), h3 = rtne_bf16(v.w);
  const u32 l0 = rtne_bf16(v.x - bf16_to_f(h0));
  const u32 l1 = rtne_bf16(v.y - bf16_to_f(h1));
  const u32 l2 = rtne_bf16(v.z - bf16_to_f(h2));
  const u32 l3 = rtne_bf16(v.w - bf16_to_f(h3));
  Who[i] = make_uint2(h0 | (h1 << 16), h2 | (h3 << 16));
  Wlo[i] = make_uint2(l0 | (l1 << 16), l2 | (l3 << 16));
}

__global__ __launch_bounds__(THREADS, 4)
void gemm_topk(const float* __restrict__ x, const u32* __restrict__ Whg,
               const u32* __restrict__ Wlg, float* __restrict__ out_probs,
               float* __restrict__ out_idx, int D) {
  __shared__ __align__(16) char smem[32768];
  // A staging: buf0 h@0 l@8192, buf1 h@16384 l@24576 (32 rows x 256B each)

  const int tid = threadIdx.x;
  const int w   = tid >> 6;
  const int l   = tid & 63;
  const int kw  = w & 3;           // K32 window within chunk
  const int eh  = w >> 2;          // expert half (0/1)
  const int m0  = blockIdx.x * TOK;
  const int nCh = D / CK;          // 32
  const int Du  = D / 2;           // u32 per W row

  const int g   = l >> 4;          // k sub-group
  const int r16 = l & 15;

  // x staging map: thread -> (row=tid>>4, blk=tid&15); 8 f32 = one 16B bf16 blk
  const int xr = tid >> 4, xc = tid & 15;
  const float* xg = x + (size_t)(m0 + xr) * D + xc * 8;

  // B fragment base offsets (u32 units), L2-hot direct-global
  const u32* wh0 = Whg + (size_t)(eh * 32 + 0  + r16) * Du + kw * 16 + g * 4;
  const u32* wh1 = Whg + (size_t)(eh * 32 + 16 + r16) * Du + kw * 16 + g * 4;
  const u32* wl0 = Wlg + (size_t)(eh * 32 + 0  + r16) * Du + kw * 16 + g * 4;
  const u32* wl1 = Wlg + (size_t)(eh * 32 + 16 + r16) * Du + kw * 16 + g * 4;

  f32x4 acc[2][2];
#pragma unroll
  for (int m = 0; m < 2; ++m)
#pragma unroll
    for (int n = 0; n < 2; ++n) acc[m][n] = (f32x4){0.f, 0.f, 0.f, 0.f};

  f32x4 xA[2], xB[2];

  // prologue: chunk0 -> xA, chunk1 -> xB; convert+publish chunk0
  xA[0] = __builtin_nontemporal_load((const f32x4*)(xg));
  xA[1] = __builtin_nontemporal_load((const f32x4*)(xg + 4));
  if (nCh > 1) {
    xB[0] = __builtin_nontemporal_load((const f32x4*)(xg + CK));
    xB[1] = __builtin_nontemporal_load((const f32x4*)(xg + CK + 4));
  }
  {
    uint4 hp, lp;
    const float f[8] = {xA[0].x, xA[0].y, xA[0].z, xA[0].w,
                        xA[1].x, xA[1].y, xA[1].z, xA[1].w};
    u32 h[8], lo[8];
#pragma unroll
    for (int i = 0; i < 8; ++i) {
      h[i]  = rtne_bf16(f[i]);
      lo[i] = rtne_bf16(f[i] - bf16_to_f(h[i]));
    }
    hp = make_uint4(h[0] | (h[1] << 16), h[2] | (h[3] << 16),
                    h[4] | (h[5] << 16), h[6] | (h[7] << 16));
    lp = make_uint4(lo[0] | (lo[1] << 16), lo[2] | (lo[3] << 16),
                    lo[4] | (lo[5] << 16), lo[6] | (lo[7] << 16));
    *(uint4*)(smem + lds_addr(0,    xr, xc)) = hp;
    *(uint4*)(smem + lds_addr(8192, xr, xc)) = lp;
  }
  __syncthreads();
  xA[0] = xB[0]; xA[1] = xB[1];    // xA = chunk1 data

  for (int c = 0; c < nCh; ++c) {
    const int buf = (c & 1) * 16384;

    // issue chunk c+2 loads (in flight for a full chunk phase)
    if (c + 2 < nCh) {
      const float* xn = xg + (size_t)(c + 2) * CK;
      xB[0] = __builtin_nontemporal_load((const f32x4*)(xn));
      xB[1] = __builtin_nontemporal_load((const f32x4*)(xn + 4));
    }

    // convert + write chunk c+1 into the other buffer
    if (c + 1 < nCh) {
      const float f[8] = {xA[0].x, xA[0].y, xA[0].z, xA[0].w,
                          xA[1].x, xA[1].y, xA[1].z, xA[1].w};
      u32 h[8], lo[8];
#pragma unroll
      for (int i = 0; i < 8; ++i) {
        h[i]  = rtne_bf16(f[i]);
        lo[i] = rtne_bf16(f[i] - bf16_to_f(h[i]));
      }
      *(uint4*)(smem + lds_addr((buf ^ 16384), xr, xc)) =
          make_uint4(h[0] | (h[1] << 16), h[2] | (h[3] << 16),
                     h[4] | (h[5] << 16), h[6] | (h[7] << 16));
      *(uint4*)(smem + lds_addr((buf ^ 16384) + 8192, xr, xc)) =
          make_uint4(lo[0] | (lo[1] << 16), lo[2] | (lo[3] << 16),
                     lo[4] | (lo[5] << 16), lo[6] | (lo[7] << 16));
    }

    // compute chunk c: A from LDS buf, B direct from global (L2-hot)
    const int blk = kw * 4 + g;
    bf16x8 ah[2], al_[2], bh[2], bl_[2];
#pragma unroll
    for (int m = 0; m < 2; ++m) {
      const int row = m * 16 + r16;
      ah[m]  = *(const bf16x8*)(smem + lds_addr(buf,        row, blk));
      al_[m] = *(const bf16x8*)(smem + lds_addr(buf + 8192, row, blk));
    }
    const size_t ko = (size_t)c * (CK / 2);
    bh[0]  = *(const bf16x8*)(wh0 + ko);
    bh[1]  = *(const bf16x8*)(wh1 + ko);
    bl_[0] = *(const bf16x8*)(wl0 + ko);
    bl_[1] = *(const bf16x8*)(wl1 + ko);
#pragma unroll
    for (int m = 0; m < 2; ++m)
#pragma unroll
      for (int n = 0; n < 2; ++n) {
        acc[m][n] = __builtin_amdgcn_mfma_f32_16x16x32_bf16(ah[m],  bh[n],  acc[m][n], 0, 0, 0);
        acc[m][n] = __builtin_amdgcn_mfma_f32_16x16x32_bf16(ah[m],  bl_[n], acc[m][n], 0, 0, 0);
        acc[m][n] = __builtin_amdgcn_mfma_f32_16x16x32_bf16(al_[m], bh[n],  acc[m][n], 0, 0, 0);
      }

    __syncthreads();   // chunk c reads done everywhere; c+1 published
    xA[0] = xB[0]; xA[1] = xB[1];
  }

  // ---- epilogue: reduce 4 k-windows, decode, top-2 ----
  float* R = (float*)smem;          // [8 waves][16 tr][64 lanes] = 32KB
#pragma unroll
  for (int m = 0; m < 2; ++m)
#pragma unroll
    for (int n = 0; n < 2; ++n)
#pragma unroll
      for (int r = 0; r < 4; ++r)
        R[w * 1024 + ((m * 2 + n) * 4 + r) * 64 + l] = acc[m][n][r];
  __syncthreads();

  // 32 tok x 64 exp = 2048 values; 512 threads x 4
  float vals[4];
  int dsti[4];
#pragma unroll
  for (int i = 0; i < 4; ++i) {
    const int j = tid + i * THREADS;
    const int t = j >> 6, e = j & 63;
    const int mm = t >> 4, nn = (e >> 4) & 1, ee = e >> 5;
    const int rr = t & 3;
    const int ll = ((t & 15) >> 2) * 16 + (e & 15);
    float v = 0.f;
#pragma unroll
    for (int k = 0; k < 4; ++k)
      v += R[(ee * 4 + k) * 1024 + ((mm * 2 + nn) * 4 + rr) * 64 + ll];
    vals[i] = v;
    dsti[i] = t * LDE + e;
  }
  __syncthreads();                  // reads done before aliasing writes
  float* Lf = (float*)smem;         // [32][68]
#pragma unroll
  for (int i = 0; i < 4; ++i) Lf[dsti[i]] = vals[i];
  __syncthreads();

  if (tid < TOK) {
    const float* row = &Lf[tid * LDE];
    float b0 = -INFINITY, b1 = -INFINITY;
    int i0 = 0, i1 = 0;
#pragma unroll
    for (int e = 0; e < NE; ++e) {   // strict '>' = lowest index on ties
      const float val = row[e];
      if (val > b0) { b1 = b0; i1 = i0; b0 = val; i0 = e; }
      else if (val > b1) { b1 = val; i1 = e; }
    }
    const float e1  = expf(b1 - b0);
    const float inv = 1.f / (1.f + e1);
    const int tok = m0 + tid;
    out_probs[tok * 2 + 0] = inv;
    out_probs[tok * 2 + 1] = e1 * inv;
    out_idx[tok * 2 + 0] = (float)i0;
    out_idx[tok * 2 + 1] = (float)i1;
  }
}

// ---- fallback (round-6 fused VALU kernel) if ws is too small ----
#define FEW 8
#define FCK 64
#define FLDT 68
#define FTOK 64
__global__ __launch_bounds__(512, 2)
void router_fused(const float* __restrict__ x, const float* __restrict__ W,
                  float* __restrict__ out_probs, float* __restrict__ out_idx,
                  int D) {
  __shared__ float As[2][FTOK][FLDT];
  const int tid = threadIdx.x;
  const int w = __builtin_amdgcn_readfirstlane(tid >> 6);
  const int lane = tid & 63;
  const int m0 = blockIdx.x * FTOK;
  const int nCh = D / FCK;
  const float* xrow = x + (size_t)(m0 + lane) * D;
  const float* __restrict__ wbase = W + (size_t)(w * FEW) * D;
  float acc[FEW];
#pragma unroll
  for (int e = 0; e < FEW; ++e) acc[e] = 0.f;
  {
    const f32x4 a = *reinterpret_cast<const f32x4*>(xrow + 4 * w);
    const f32x4 b = *reinterpret_cast<const f32x4*>(xrow + 4 * (w + 8));
    *reinterpret_cast<f32x4*>(&As[0][lane][4 * w]) = a;
    *reinterpret_cast<f32x4*>(&As[0][lane][4 * (w + 8)]) = b;
  }
  __syncthreads();
  for (int c = 0; c < nCh; ++c) {
    const int buf = c & 1;
    f32x4 na, nb;
    const bool more = (c + 1 < nCh);
    if (more) {
      const float* xn = xrow + (size_t)(c + 1) * FCK;
      na = *reinterpret_cast<const f32x4*>(xn + 4 * w);
      nb = *reinterpret_cast<const f32x4*>(xn + 4 * (w + 8));
    }
    const float* __restrict__ wp = wbase + (size_t)c * FCK;
#pragma unroll 2
    for (int kk = 0; kk < FCK / 4; ++kk) {
      const f32x4 xvv = *reinterpret_cast<const f32x4*>(&As[buf][lane][kk * 4]);
#pragma unroll
      for (int e = 0; e < FEW; ++e) {
        const f32x4 wv = *reinterpret_cast<const f32x4*>(wp + (size_t)e * D + kk * 4);
        acc[e] = fmaf(xvv.x, wv.x, acc[e]);
        acc[e] = fmaf(xvv.y, wv.y, acc[e]);
        acc[e] = fmaf(xvv.z, wv.z, acc[e]);
        acc[e] = fmaf(xvv.w, wv.w, acc[e]);
      }
    }
    __syncthreads();
    if (more) {
      *reinterpret_cast<f32x4*>(&As[buf ^ 1][lane][4 * w]) = na;
      *reinterpret_cast<f32x4*>(&As[buf ^ 1][lane][4 * (w + 8)]) = nb;
    }
    __syncthreads();
  }
  float* L = &As[0][0][0];
  *reinterpret_cast<f32x4*>(&L[lane * FLDT + w * FEW + 0]) =
      (f32x4){acc[0], acc[1], acc[2], acc[3]};
  *reinterpret_cast<f32x4*>(&L[lane * FLDT + w * FEW + 4]) =
      (f32x4){acc[4], acc[5], acc[6], acc[7]};
  __syncthreads();
  if (tid < FTOK) {
    const float* row = &L[tid * FLDT];
    float b0 = -INFINITY, b1 = -INFINITY;
    int i0 = 0, i1 = 0;
#pragma unroll
    for (int e = 0; e < NE; ++e) {
      const float val = row[e];
      if (val > b0) { b1 = b0; i1 = i0; b0 = val; i0 = e; }
      else if (val > b1) { b1 = val; i1 = e; }
    }
    const float e1 = expf(b1 - b0);
    const float inv = 1.f / (1.f + e1);
    const int tok = m0 + tid;
    out_probs[tok * 2 + 0] = inv;
    out_probs[tok * 2 + 1] = e1 * inv;
    out_idx[tok * 2 + 0] = (float)i0;
    out_idx[tok * 2 + 1] = (float)i1;
  }
}

extern "C" void kernel_launch(void* const* d_in, const int* in_sizes, int n_in,
                              void* d_out, int out_size, void* d_ws, size_t ws_size,
                              hipStream_t stream) {
  const float* x = (const float*)d_in[0];
  const float* W = (const float*)d_in[1];

  const int E = 64;
  const int D = in_sizes[1] / E;            // 4096
  const int nTok = in_sizes[0] / D;         // 16384

  float* probs = (float*)d_out;
  float* idxo  = (float*)d_out + (size_t)nTok * 2;

  const size_t wBytes = (size_t)E * D * sizeof(short);   // 512 KB per half
  if (ws_size >= 2 * wBytes) {
    u32* Wh = (u32*)d_ws;
    u32* Wl = (u32*)((char*)d_ws + wBytes);
    hipLaunchKernelGGL(wprep, dim3((E * D / 4) / 256), dim3(256), 0, stream,
                       W, (uint2*)Wh, (uint2*)Wl);
    hipLaunchKernelGGL(gemm_topk, dim3(nTok / TOK), dim3(THREADS), 0, stream,
                       x, Wh, Wl, probs, idxo, D);
  } else {
    hipLaunchKernelGGL(router_fused, dim3(nTok / FTOK), dim3(512), 0, stream,
                       x, W, probs, idxo, D);
  }
}